// Round 7
// baseline (471.414 us; speedup 1.0000x reference)
//
#include <hip/hip_runtime.h>

#define N_NODES 50000
#define N_EDGES 800000
#define IN_C 256
#define HID_C 512
#define OUT_C 256
#define M_PAD 50048   // 391 * 128, covers 50000 with one padded tile
#define NPASS 8
#define PASS_SHIFT 13   // src >> 13 -> bucket (8192-node source windows)

typedef unsigned short u16;
typedef unsigned int   u32;
typedef u16  u16x4 __attribute__((ext_vector_type(4)));
typedef u16  u16x8 __attribute__((ext_vector_type(8)));
typedef short s16x8 __attribute__((ext_vector_type(8)));   // bf16 MFMA frag (guide §3)
typedef float f32x4 __attribute__((ext_vector_type(4)));
typedef int   s32x4 __attribute__((ext_vector_type(4)));

__device__ __forceinline__ float bf2f(u16 h) {
    u32 u = ((u32)h) << 16;
    return __builtin_bit_cast(float, u);
}
__device__ __forceinline__ u16 f2bf(float f) {   // round-to-nearest-even
    u32 u = __builtin_bit_cast(u32, f);
    u32 r = u + 0x7fffu + ((u >> 16) & 1u);
    return (u16)(r >> 16);
}
__device__ __forceinline__ void gload16(const void* g, void* l) {
    __builtin_amdgcn_global_load_lds(
        (const __attribute__((address_space(1))) u32*)g,
        (__attribute__((address_space(3))) u32*)l, 16, 0, 0);
}

// ---------------- sub-CSR build: buckets (dst, src>>13) ----------------
// col ends up sorted by (dst, src>>13): per node the edge list is contiguous
// [rp8[n*8], rp8[n*8+8]) AND pass-sorted (source-window-ascending).
__global__ void k_hist8(const int* __restrict__ src, const int* __restrict__ dst,
                        int* __restrict__ cnt8) {
    int e = blockIdx.x * 256 + threadIdx.x;
    if (e < N_EDGES) {
        int q = src[e] >> PASS_SHIFT;
        atomicAdd(&cnt8[dst[e] * NPASS + q], 1);
    }
}

__global__ void k_partial(const int* __restrict__ cnt, int* __restrict__ bsum, int total) {
    __shared__ int s[256];
    int i = blockIdx.x * 256 + threadIdx.x;
    int v = (i < total) ? cnt[i] : 0;
    s[threadIdx.x] = v; __syncthreads();
    for (int o = 128; o > 0; o >>= 1) {
        if (threadIdx.x < o) s[threadIdx.x] += s[threadIdx.x + o];
        __syncthreads();
    }
    if (threadIdx.x == 0) bsum[blockIdx.x] = s[0];
}

// exclusive scan of nb block sums (nb may exceed 256): chunked Hillis-Steele + carry
__global__ void k_scanb(int* __restrict__ bsum, int nb) {
    __shared__ int s[256];
    int carry = 0;
    for (int base = 0; base < nb; base += 256) {
        int i = base + threadIdx.x;
        int v = (i < nb) ? bsum[i] : 0;
        s[threadIdx.x] = v; __syncthreads();
        for (int o = 1; o < 256; o <<= 1) {
            int t = (threadIdx.x >= o) ? s[threadIdx.x - o] : 0;
            __syncthreads();
            s[threadIdx.x] += t;
            __syncthreads();
        }
        int tot = s[255];
        if (i < nb) bsum[i] = s[threadIdx.x] - v + carry;
        carry += tot;
        __syncthreads();
    }
}

__global__ void k_rowptr8(const int* __restrict__ cnt, const int* __restrict__ bsum,
                          int* __restrict__ rp, int* __restrict__ cur, int total) {
    __shared__ int s[256];
    int i = blockIdx.x * 256 + threadIdx.x;
    int v = (i < total) ? cnt[i] : 0;
    s[threadIdx.x] = v; __syncthreads();
    for (int o = 1; o < 256; o <<= 1) {                     // Hillis-Steele inclusive
        int t = (threadIdx.x >= o) ? s[threadIdx.x - o] : 0;
        __syncthreads();
        s[threadIdx.x] += t;
        __syncthreads();
    }
    int excl = s[threadIdx.x] - v + bsum[blockIdx.x];
    if (i < total) { rp[i] = excl; cur[i] = excl; }
    if (i == total - 1) rp[total] = excl + v;
}

__global__ void k_scatter8(const int* __restrict__ src, const int* __restrict__ dst,
                           int* __restrict__ cur, int* __restrict__ col) {
    int e = blockIdx.x * 256 + threadIdx.x;
    if (e < N_EDGES) {
        int sv = src[e];
        int q = sv >> PASS_SHIFT;
        int p = atomicAdd(&cur[dst[e] * NPASS + q], 1);
        col[p] = sv;
    }
}

// ------ merged prep: w1t/w2t/w3t transposed bf16 + x -> bf16 (one launch) ------
__device__ __forceinline__ void wt_body(const float* w, u16* wt, int K, int N, int idx) {
    if (idx >= K * N) return;
    int n = idx / K, k = idx - n * K;
    wt[idx] = f2bf(w[(size_t)k * N + n]);
}

__global__ void k_prep(const float* __restrict__ w1, const float* __restrict__ w2,
                       const float* __restrict__ w3, const float* __restrict__ x,
                       u16* __restrict__ w1t, u16* __restrict__ w2t,
                       u16* __restrict__ w3t, u16* __restrict__ xb) {
    int b = blockIdx.x, t = threadIdx.x;
    if (b < 512) {
        wt_body(w1, w1t, IN_C, HID_C, b * 256 + t);
    } else if (b < 1536) {
        wt_body(w2, w2t, HID_C, HID_C, (b - 512) * 256 + t);
    } else if (b < 2048) {
        wt_body(w3, w3t, HID_C, OUT_C, (b - 1536) * 256 + t);
    } else {
        int i = (b - 2048) * 256 + t;
        if (i < N_NODES * IN_C / 4) {
            float4 v = ((const float4*)x)[i];
            u16x4 o;
            o[0] = f2bf(v.x); o[1] = f2bf(v.y); o[2] = f2bf(v.z); o[3] = f2bf(v.w);
            ((u16x4*)xb)[i] = o;
        }
    }
}

// ---- streaming slab gather (XCD-private lines, high-MLP form) ----
// 128-B slabs: C=512 -> 8 slabs, slab=bid&7 -> each line pulled by exactly one
// XCD; C=256 -> 4 slabs, 2 XCDs per slab.
// One node per 8-lane group (32 nodes/block, 8 nodes/wave); lane owns 8 ch
// (16 B = dwordx4) -> full 1KB/wave gather instructions, 32 lines in flight
// per wave at 4-deep unroll. col read via aligned int4 (1 VMEM / 4 edges),
// nontemporal so index streams don't evict gather lines. 32-bit offsets.
// EPI 0: out bf16 = bf16(ep*self + agg).  EPI 1: out fp32 = ep*self + agg + bias.
template <int C, int EPI>
__global__ __launch_bounds__(256) void k_agg_stream(
    const u16* __restrict__ sm, const int* __restrict__ rp8,
    const int* __restrict__ col, const float* __restrict__ eps,
    const float* __restrict__ bias, void* __restrict__ out) {
    constexpr int NSLAB = C / 64;          // 128-B slabs
    const int slab  = blockIdx.x & (NSLAB - 1);
    const int chunk = blockIdx.x / NSLAB;
    const int gid = threadIdx.x >> 3;      // 32 groups of 8 lanes
    const int ln  = threadIdx.x & 7;
    const u32 ch0 = slab * 64 + ln * 8;
    const int n = chunk * 32 + gid;
    if (n >= N_NODES) return;
    const float ep = 1.f + eps[0];

    const int rs = __builtin_nontemporal_load(rp8 + n * NPASS);
    const int re = __builtin_nontemporal_load(rp8 + n * NPASS + NPASS);

    float a[8];
#pragma unroll
    for (int j = 0; j < 8; j++) a[j] = 0.f;

    int e = rs;
    {   // scalar prologue to 4-align e for int4 col loads
        int pro = (4 - (e & 3)) & 3;
        if (pro > re - rs) pro = re - rs;
        for (int i = 0; i < pro; i++, e++) {
            int s0 = col[e];
            u16x8 v0 = *(const u16x8*)(sm + (u32)s0 * C + ch0);
#pragma unroll
            for (int j = 0; j < 8; j++) a[j] += bf2f(v0[j]);
        }
    }
    for (; e + 4 <= re; e += 4) {
        s32x4 c4 = __builtin_nontemporal_load((const s32x4*)(col + e));
        u16x8 v0 = *(const u16x8*)(sm + (u32)c4[0] * C + ch0);
        u16x8 v1 = *(const u16x8*)(sm + (u32)c4[1] * C + ch0);
        u16x8 v2 = *(const u16x8*)(sm + (u32)c4[2] * C + ch0);
        u16x8 v3 = *(const u16x8*)(sm + (u32)c4[3] * C + ch0);
#pragma unroll
        for (int j = 0; j < 8; j++)
            a[j] += (bf2f(v0[j]) + bf2f(v1[j])) + (bf2f(v2[j]) + bf2f(v3[j]));
    }
    for (; e < re; e++) {
        int s0 = col[e];
        u16x8 v0 = *(const u16x8*)(sm + (u32)s0 * C + ch0);
#pragma unroll
        for (int j = 0; j < 8; j++) a[j] += bf2f(v0[j]);
    }

    u16x8 sv = *(const u16x8*)(sm + (u32)n * C + ch0);
    float r[8];
#pragma unroll
    for (int j = 0; j < 8; j++) r[j] = fmaf(ep, bf2f(sv[j]), a[j]);

    if constexpr (EPI == 0) {
        u16x8 o;
#pragma unroll
        for (int j = 0; j < 8; j++) o[j] = f2bf(r[j]);
        *(u16x8*)((u16*)out + (u32)n * C + ch0) = o;
    } else {
        float4 b0 = *(const float4*)(bias + ch0);
        float4 b1 = *(const float4*)(bias + ch0 + 4);
        float* orow = (float*)out + (u32)n * C + ch0;
        float4 o0, o1;
        o0.x = r[0] + b0.x; o0.y = r[1] + b0.y; o0.z = r[2] + b0.z; o0.w = r[3] + b0.w;
        o1.x = r[4] + b1.x; o1.y = r[5] + b1.y; o1.z = r[6] + b1.z; o1.w = r[7] + b1.w;
        *(float4*)orow = o0;
        *(float4*)(orow + 4) = o1;
    }
}

// -------------- bf16 MFMA GEMM: C[M][N] = A[M][K] @ Wt[N][K]^T --------------
// 128x128 tile, BK=64 (32 MFMA per vmcnt/barrier drain), 4 waves (2x2).
// Staging: global_load_lds w16, linear LDS dest, chunk-XOR swizzle c^=(r&7)
// applied on BOTH global source and ds_read (rule 21) -> 2-way (free) banks.
// Epilogue: acc -> bf16 -> LDS C-tile [128][130] (pad => conflict-free b128
// readback), then coalesced u16x8 global stores.
// EPI=0: out bf16 = relu(acc + bias).  EPI=1: out bf16 = acc.
template <int K, int EPI>
__global__ __launch_bounds__(256, 2) void gemm_k(
    const u16* __restrict__ A, const u16* __restrict__ Wt,
    const float* __restrict__ bias, void* __restrict__ out,
    int N, int grid_n) {
    __shared__ u16 smem[16640];            // max(Als+Bls = 16384, Cls = 16640)
    u16* Als = smem;                       // [128][64]
    u16* Bls = smem + 8192;                // [128][64]
    const int tid  = threadIdx.x;
    const int wave = tid >> 6, lane = tid & 63;
    const int wm = wave >> 1, wn = wave & 1;
    const int bm = blockIdx.x / grid_n, bn = blockIdx.x % grid_n;
    const int m0 = bm * 128, n0 = bn * 128;
    const int sr = lane >> 3, sc = lane & 7;       // staging: 8 rows x 8 chunks
    const int fr = lane & 15, kg = lane >> 4;      // fragment coords

    f32x4 acc[4][4];
#pragma unroll
    for (int i = 0; i < 4; i++)
#pragma unroll
        for (int j = 0; j < 4; j++) acc[i][j] = (f32x4){0.f, 0.f, 0.f, 0.f};

    for (int kk = 0; kk < K; kk += 64) {
#pragma unroll
        for (int i = 0; i < 4; i++) {
            int rl = wave * 32 + i * 8 + sr;
            int cs = sc ^ (rl & 7);                 // pre-swizzled global source
            gload16(A  + (size_t)(m0 + rl) * K + kk + cs * 8,
                    &Als[(wave * 32 + i * 8) * 64]);
            gload16(Wt + (size_t)(n0 + rl) * K + kk + cs * 8,
                    &Bls[(wave * 32 + i * 8) * 64]);
        }
        asm volatile("s_waitcnt vmcnt(0)" ::: "memory");
        __syncthreads();

#pragma unroll
        for (int k2 = 0; k2 < 2; k2++) {
            s16x8 af[4], bfr[4];
#pragma unroll
            for (int mi = 0; mi < 4; mi++) {
                int r = wm * 64 + mi * 16 + fr;
                int c = (k2 * 4 + kg) ^ (r & 7);    // swizzled read
                af[mi] = *(const s16x8*)&Als[r * 64 + c * 8];
            }
#pragma unroll
            for (int ni = 0; ni < 4; ni++) {
                int r = wn * 64 + ni * 16 + fr;
                int c = (k2 * 4 + kg) ^ (r & 7);
                bfr[ni] = *(const s16x8*)&Bls[r * 64 + c * 8];
            }
#pragma unroll
            for (int mi = 0; mi < 4; mi++)
#pragma unroll
                for (int ni = 0; ni < 4; ni++)
                    acc[mi][ni] = __builtin_amdgcn_mfma_f32_16x16x32_bf16(
                        af[mi], bfr[ni], acc[mi][ni], 0, 0, 0);
        }
        __syncthreads();
    }

    // epilogue: C row = kg*4 + j, col = fr (m89/m91-verified C/D layout)
    // bounce through LDS [128][130] for coalesced output
    u16* Cls = smem;
#pragma unroll
    for (int ni = 0; ni < 4; ni++) {
        int c = wn * 64 + ni * 16 + fr;
        float bv = 0.f;
        if constexpr (EPI == 0) bv = bias[n0 + c];
#pragma unroll
        for (int mi = 0; mi < 4; mi++) {
#pragma unroll
            for (int j = 0; j < 4; j++) {
                int r = wm * 64 + mi * 16 + kg * 4 + j;
                float v = acc[mi][ni][j];
                if constexpr (EPI == 0) {
                    v += bv;
                    v = v > 0.f ? v : 0.f;
                }
                Cls[r * 130 + c] = f2bf(v);
            }
        }
    }
    __syncthreads();

    const int r2 = tid >> 1;                  // 0..127
    const int cb = (tid & 1) * 64;            // two 64-col halves
    if (m0 + r2 < N_NODES) {
        u16* orow = (u16*)out + (size_t)(m0 + r2) * N + n0 + cb;
#pragma unroll
        for (int k = 0; k < 8; k++) {
            u16x8 val = *(const u16x8*)&Cls[r2 * 130 + cb + k * 8];
            *(u16x8*)(orow + k * 8) = val;
        }
    }
}

// ---------------- launch ----------------
extern "C" void kernel_launch(void* const* d_in, const int* in_sizes, int n_in,
                              void* d_out, int out_size, void* d_ws, size_t ws_size,
                              hipStream_t stream) {
    const float* x    = (const float*)d_in[0];
    const int*   src  = (const int*)d_in[1];
    const int*   dst  = (const int*)d_in[2];
    const float* w1   = (const float*)d_in[3];
    const float* b1   = (const float*)d_in[4];
    const float* eps1 = (const float*)d_in[5];
    const float* w2   = (const float*)d_in[6];
    const float* b2   = (const float*)d_in[7];
    const float* eps2 = (const float*)d_in[8];
    const float* w3   = (const float*)d_in[9];
    const float* b3   = (const float*)d_in[10];
    const float* eps3 = (const float*)d_in[11];

    char* ws = (char*)d_ws;
    size_t off = 0;
    auto take = [&](size_t bytes) {
        char* p = ws + off;
        off += (bytes + 255) & ~(size_t)255;
        return p;
    };
    const int TOT8 = N_NODES * NPASS;                 // 400000 buckets
    int* cnt8 = (int*)take((size_t)TOT8 * 4);
    int* rp8  = (int*)take((size_t)(TOT8 + 1) * 4);
    int* cur8 = (int*)take((size_t)TOT8 * 4);
    int* bsum = (int*)take(2048 * 4);
    int* col  = (int*)take((size_t)N_EDGES * 4);
    u16* w1t  = (u16*)take((size_t)IN_C * HID_C * 2);
    u16* w2t  = (u16*)take((size_t)HID_C * HID_C * 2);
    u16* w3t  = (u16*)take((size_t)HID_C * OUT_C * 2);
    u16* A0   = (u16*)take((size_t)M_PAD * IN_C * 2);
    u16* h1   = (u16*)take((size_t)M_PAD * HID_C * 2);
    u16* A1   = (u16*)take((size_t)M_PAD * HID_C * 2);
    // time-shared buffer: xb (phase 1) -> A1 (phase 2) -> g3 bf16 (phase 3).
    // each is fully dead before the next is written; stream order serializes.
    u16* xb = A1;            // 25.6 MB <= 51.2 MB, dead after l1 agg
    u16* h2 = h1;            // GEMM2 reads only A1 -> safe alias
    u16* g3 = A1;            // GEMM3 reads only h2 -> safe alias

    const int NB8 = (TOT8 + 255) / 256;   // 1563 scan blocks
    const int NE  = (N_EDGES + 255) / 256;

    hipMemsetAsync(cnt8, 0, (size_t)TOT8 * 4, stream);
    k_hist8  <<<NE, 256, 0, stream>>>(src, dst, cnt8);
    k_partial<<<NB8, 256, 0, stream>>>(cnt8, bsum, TOT8);
    k_scanb  <<<1, 256, 0, stream>>>(bsum, NB8);
    k_rowptr8<<<NB8, 256, 0, stream>>>(cnt8, bsum, rp8, cur8, TOT8);
    k_scatter8<<<NE, 256, 0, stream>>>(src, dst, cur8, col);

    // merged prep: 2048 weight-transpose blocks + 12500 x->bf16 blocks
    k_prep<<<2048 + 12500, 256, 0, stream>>>(w1, w2, w3, x, w1t, w2t, w3t, xb);

    // agg grids: 32 nodes/block; C=512 -> 1563 chunks x 8 slabs; C=256 -> x 4
    const int NCH  = (N_NODES + 31) / 32;   // 1563
    const int G512 = NCH * 8;
    const int G256 = NCH * 4;

    // layer 1: aggregate (256ch bf16) then GEMM -> h1 = relu(A0 @ W1 + b1)
    k_agg_stream<IN_C, 0><<<G256, 256, 0, stream>>>(xb, rp8, col, eps1, nullptr, A0);
    gemm_k<IN_C, 0><<<391 * (HID_C / 128), 256, 0, stream>>>(
        A0, w1t, b1, h1, HID_C, HID_C / 128);

    // layer 2: aggregate (512ch) then GEMM -> h2 = relu(A1 @ W2 + b2)
    k_agg_stream<HID_C, 0><<<G512, 256, 0, stream>>>(h1, rp8, col, eps2, nullptr, A1);
    gemm_k<HID_C, 0><<<391 * (HID_C / 128), 256, 0, stream>>>(
        A1, w2t, b2, h2, HID_C, HID_C / 128);

    // layer 3: GEMM first (g3 = h2 @ W3 bf16, no bias), then aggregate + bias -> fp32
    gemm_k<HID_C, 1><<<391 * (OUT_C / 128), 256, 0, stream>>>(
        h2, w3t, nullptr, g3, OUT_C, OUT_C / 128);
    k_agg_stream<OUT_C, 1><<<G256, 256, 0, stream>>>(g3, rp8, col, eps3, b3, (float*)d_out);
}